// Round 1
// baseline (1968.933 us; speedup 1.0000x reference)
//
#include <hip/hip_runtime.h>
#include <stdint.h>

// ---------------- common ----------------
typedef float f32x4 __attribute__((ext_vector_type(4)));
typedef const __attribute__((address_space(1))) void* gp1_t;
typedef __attribute__((address_space(3))) void* lp3_t;

__device__ __forceinline__ void gload_lds16(const void* g, void* l) {
  __builtin_amdgcn_global_load_lds((gp1_t)g, (lp3_t)l, 16, 0, 0);
}

__device__ __forceinline__ uint32_t pack4_fp8(float a, float b, float c, float d) {
  a = fminf(fmaxf(a, -448.f), 448.f);
  b = fminf(fmaxf(b, -448.f), 448.f);
  c = fminf(fmaxf(c, -448.f), 448.f);
  d = fminf(fmaxf(d, -448.f), 448.f);
  uint32_t v = 0;
  v = __builtin_amdgcn_cvt_pk_fp8_f32(a, b, v, false);  // bytes 0,1
  v = __builtin_amdgcn_cvt_pk_fp8_f32(c, d, v, true);   // bytes 2,3
  return v;
}

// Each thread converts 16 consecutive floats -> 16 fp8 bytes (one uint4 store).
__global__ __launch_bounds__(256) void quant_fp8(const float* __restrict__ in,
                                                 uint4* __restrict__ out) {
  size_t t = (size_t)blockIdx.x * 256 + threadIdx.x;
  const float4* in4 = (const float4*)in;
  float4 v0 = in4[t * 4 + 0];
  float4 v1 = in4[t * 4 + 1];
  float4 v2 = in4[t * 4 + 2];
  float4 v3 = in4[t * 4 + 3];
  uint4 r;
  r.x = pack4_fp8(v0.x, v0.y, v0.z, v0.w);
  r.y = pack4_fp8(v1.x, v1.y, v1.z, v1.w);
  r.z = pack4_fp8(v2.x, v2.y, v2.z, v2.w);
  r.w = pack4_fp8(v3.x, v3.y, v3.z, v3.w);
  out[t] = r;
}

// ---------------- 256x256 8-phase fp8 GEMM ----------------
// C[M,N] = A[M,K](fp8) * B[N,K](fp8)^T + bias, fp32 accumulate.
// 512 threads = 8 waves (2M x 4N), per-wave 128x64 output (8x4 frags of 16x16).
// BK=64, quad-buffered LDS (4 x 32KB), 4 phases per K-tile, 16 MFMA/phase.
// Counted vmcnt(8) once per K-tile (3 K-tiles in flight), never drained to 0.
// LDS XOR swizzle: physical col = logical col ^ ((row&3)<<4)  (bits 4-5 only,
// so 16B global_load_lds chunks stay contiguous; inverse applied on the
// global source address, forward on ds_read addresses — involution).
#define BM 256
#define BN 256
#define BKT 64
#define BUFSZ 32768  // A half: 256*64 = 16KB, B half: 16KB
#define BOFF 16384

__global__ __launch_bounds__(512, 2) void gemm_fp8(const uint8_t* __restrict__ A,
                                                   const uint8_t* __restrict__ B,
                                                   const float* __restrict__ bias,
                                                   float* __restrict__ C,
                                                   int M, int N, int K) {
  __shared__ uint8_t lds[4 * BUFSZ];  // 128 KiB

  const int num_m = M / BM;  // 32
  const int num_n = N / BN;  // 64

  // Bijective XCD swizzle (nwg = 2048, divisible by 8): XCD k gets a
  // contiguous chunk of swz; m varies fastest within a chunk (B-panel reuse).
  const int nwg = num_m * num_n;
  const int cpx = nwg >> 3;
  const int bid = blockIdx.x;
  const int swz = (bid & 7) * cpx + (bid >> 3);
  const int tile_m = swz % num_m;
  const int tile_n = swz / num_m;

  const int tid = threadIdx.x;
  const int lane = tid & 63;
  const int wid = tid >> 6;
  const int wm = wid >> 2;  // 0..1
  const int wn = wid & 3;   // 0..3
  const int lm = lane & 15;
  const int quad = lane >> 4;

  const size_t m0 = (size_t)tile_m * BM;
  const size_t n0 = (size_t)tile_n * BN;

  // Staging: thread stages one 16B chunk per half-tile. Physical LDS dest is
  // linear (region + tid*16, wave-uniform base + lane*16). Global source is
  // inverse-swizzled so logical col c lands at physical p = c ^ ((row&3)<<4).
  const int srow = tid >> 2;          // 0..127 (row within half)
  const int spc = (tid & 3) << 4;     // physical 16B chunk
  const int scol = spc ^ ((srow & 3) << 4);
  const uint8_t* agA = A + (m0 + srow) * (size_t)K + scol;
  const uint8_t* agB = B + (n0 + srow) * (size_t)K + scol;
  const size_t halfK = (size_t)128 * K;

  // ds_read lane offsets (swizzled): logical col = ks*32 + quad*8.
  const int cs0 = (quad * 8) ^ ((lm & 3) << 4);
  const int cs1 = (32 + quad * 8) ^ ((lm & 3) << 4);
  const int arow = (wm * 128 + lm) * 64;        // + mh*4096 + i*1024
  const int brow = BOFF + (wn * 64 + lm) * 64;  // + nh*2048 + j*1024

  f32x4 acc[8][4] = {};
  long a[8], bl[4], bh[4];

  const int NT = K >> 6;  // 64 K-tiles

  // Prologue: stage K-tiles 0..2 (12 loads/thread), wait tile 0 (vmcnt 8).
  for (int t = 0; t < 3; ++t) {
    uint8_t* buf = lds + t * BUFSZ;
    const uint8_t* ka = agA + (size_t)t * BKT;
    const uint8_t* kb = agB + (size_t)t * BKT;
    gload_lds16(ka, buf + tid * 16);
    gload_lds16(ka + halfK, buf + 8192 + tid * 16);
    gload_lds16(kb, buf + BOFF + tid * 16);
    gload_lds16(kb + halfK, buf + BOFF + 8192 + tid * 16);
  }
  asm volatile("s_waitcnt vmcnt(8)" ::: "memory");
  __builtin_amdgcn_s_barrier();

  for (int t = 0; t < NT; ++t) {
    const uint8_t* bufc = lds + (t & 3) * BUFSZ;
    uint8_t* bufs = lds + ((t + 3) & 3) * BUFSZ;
    const bool do_stage = (t + 3) < NT;
    const uint8_t* ka = agA + (size_t)(t + 3) * BKT;
    const uint8_t* kb = agB + (size_t)(t + 3) * BKT;
    const uint8_t* pa0 = bufc + arow + cs0;
    const uint8_t* pa1 = bufc + arow + cs1;
    const uint8_t* pb0 = bufc + brow + cs0;
    const uint8_t* pb1 = bufc + brow + cs1;

    // ---- phase 0: quadrant (m-lo, n-lo); stage A-lo of tile t+3 ----
#pragma unroll
    for (int i = 0; i < 4; ++i) {
      a[i * 2 + 0] = *(const long*)(pa0 + i * 1024);
      a[i * 2 + 1] = *(const long*)(pa1 + i * 1024);
    }
#pragma unroll
    for (int j = 0; j < 2; ++j) {
      bl[j * 2 + 0] = *(const long*)(pb0 + j * 1024);
      bl[j * 2 + 1] = *(const long*)(pb1 + j * 1024);
    }
    if (do_stage) gload_lds16(ka, bufs + tid * 16);
    asm volatile("" ::: "memory");
    __builtin_amdgcn_s_barrier();
    asm volatile("s_waitcnt lgkmcnt(0)" ::: "memory");
    __builtin_amdgcn_s_setprio(1);
#pragma unroll
    for (int ks = 0; ks < 2; ++ks)
#pragma unroll
      for (int i = 0; i < 4; ++i)
#pragma unroll
        for (int j = 0; j < 2; ++j)
          acc[i][j] = __builtin_amdgcn_mfma_f32_16x16x32_fp8_fp8(
              a[i * 2 + ks], bl[j * 2 + ks], acc[i][j], 0, 0, 0);
    __builtin_amdgcn_s_setprio(0);
    __builtin_amdgcn_s_barrier();

    // ---- phase 1: quadrant (m-lo, n-hi); stage A-hi ----
#pragma unroll
    for (int j = 0; j < 2; ++j) {
      bh[j * 2 + 0] = *(const long*)(pb0 + 2048 + j * 1024);
      bh[j * 2 + 1] = *(const long*)(pb1 + 2048 + j * 1024);
    }
    if (do_stage) gload_lds16(ka + halfK, bufs + 8192 + tid * 16);
    asm volatile("" ::: "memory");
    __builtin_amdgcn_s_barrier();
    asm volatile("s_waitcnt lgkmcnt(0)" ::: "memory");
    __builtin_amdgcn_s_setprio(1);
#pragma unroll
    for (int ks = 0; ks < 2; ++ks)
#pragma unroll
      for (int i = 0; i < 4; ++i)
#pragma unroll
        for (int j = 0; j < 2; ++j)
          acc[i][2 + j] = __builtin_amdgcn_mfma_f32_16x16x32_fp8_fp8(
              a[i * 2 + ks], bh[j * 2 + ks], acc[i][2 + j], 0, 0, 0);
    __builtin_amdgcn_s_setprio(0);
    __builtin_amdgcn_s_barrier();

    // ---- phase 2: quadrant (m-hi, n-hi); stage B-lo ----
#pragma unroll
    for (int i = 0; i < 4; ++i) {
      a[i * 2 + 0] = *(const long*)(pa0 + 4096 + i * 1024);
      a[i * 2 + 1] = *(const long*)(pa1 + 4096 + i * 1024);
    }
    if (do_stage) gload_lds16(kb, bufs + BOFF + tid * 16);
    asm volatile("" ::: "memory");
    __builtin_amdgcn_s_barrier();
    asm volatile("s_waitcnt lgkmcnt(0)" ::: "memory");
    __builtin_amdgcn_s_setprio(1);
#pragma unroll
    for (int ks = 0; ks < 2; ++ks)
#pragma unroll
      for (int i = 0; i < 4; ++i)
#pragma unroll
        for (int j = 0; j < 2; ++j)
          acc[4 + i][2 + j] = __builtin_amdgcn_mfma_f32_16x16x32_fp8_fp8(
              a[i * 2 + ks], bh[j * 2 + ks], acc[4 + i][2 + j], 0, 0, 0);
    __builtin_amdgcn_s_setprio(0);
    __builtin_amdgcn_s_barrier();

    // ---- phase 3: quadrant (m-hi, n-lo); stage B-hi; counted vmcnt ----
    if (do_stage) gload_lds16(kb + halfK, bufs + BOFF + 8192 + tid * 16);
    asm volatile("" ::: "memory");
    __builtin_amdgcn_s_barrier();
    asm volatile("s_waitcnt lgkmcnt(0)" ::: "memory");
    __builtin_amdgcn_s_setprio(1);
#pragma unroll
    for (int ks = 0; ks < 2; ++ks)
#pragma unroll
      for (int i = 0; i < 4; ++i)
#pragma unroll
        for (int j = 0; j < 2; ++j)
          acc[4 + i][j] = __builtin_amdgcn_mfma_f32_16x16x32_fp8_fp8(
              a[i * 2 + ks], bl[j * 2 + ks], acc[4 + i][j], 0, 0, 0);
    __builtin_amdgcn_s_setprio(0);
    // Guarantee tile t+1's 4 loads (oldest) have landed before any wave
    // crosses into its ds_reads. Steady state: 12 outstanding, keep 8.
    if (t < NT - 3) {
      asm volatile("s_waitcnt vmcnt(8)" ::: "memory");
    } else if (t == NT - 3) {
      asm volatile("s_waitcnt vmcnt(4)" ::: "memory");
    } else if (t == NT - 2) {
      asm volatile("s_waitcnt vmcnt(0)" ::: "memory");
    }
    __builtin_amdgcn_s_barrier();
  }

  // Epilogue: C/D layout col = lane&15, row = quad*4 + reg (m89-verified).
  const int row_base = (int)m0 + wm * 128 + quad * 4;
  const int col_base = (int)n0 + wn * 64 + lm;
#pragma unroll
  for (int nj = 0; nj < 4; ++nj) {
    int col = col_base + nj * 16;
    float bv = bias[col];
#pragma unroll
    for (int mi = 0; mi < 8; ++mi) {
      int row = row_base + mi * 16;
#pragma unroll
      for (int r = 0; r < 4; ++r) {
        __builtin_nontemporal_store(acc[mi][nj][r] + bv,
                                    C + (size_t)(row + r) * N + col);
      }
    }
  }
}

extern "C" void kernel_launch(void* const* d_in, const int* in_sizes, int n_in,
                              void* d_out, int out_size, void* d_ws, size_t ws_size,
                              hipStream_t stream) {
  const float* x = (const float*)d_in[0];
  const float* W = (const float*)d_in[1];
  const float* bias = (const float*)d_in[2];
  float* out = (float*)d_out;

  const int N = in_sizes[2];      // 16384
  const int K = in_sizes[1] / N;  // 4096
  const int M = in_sizes[0] / K;  // 8192

  uint8_t* Xq = (uint8_t*)d_ws;
  uint8_t* Wq = Xq + (size_t)M * K;

  // fp32 -> fp8 e4m3fn (RNE, matches ml_dtypes), clamp +-448 per reference.
  {
    int blocks_x = (int)(((size_t)M * K) / (16 * 256));
    quant_fp8<<<blocks_x, 256, 0, stream>>>(x, (uint4*)Xq);
    int blocks_w = (int)(((size_t)N * K) / (16 * 256));
    quant_fp8<<<blocks_w, 256, 0, stream>>>(W, (uint4*)Wq);
  }

  int grid = (M / BM) * (N / BN);  // 32 * 64 = 2048
  gemm_fp8<<<grid, 512, 0, stream>>>(Xq, Wq, bias, out, M, N, K);
}